// Round 7
// baseline (194.204 us; speedup 1.0000x reference)
//
#include <hip/hip_runtime.h>
#include <stdint.h>

// Problem constants (fixed by setup_inputs: B=2,H=16,N=2048,D=128), f32 in/out.
#define NN 2048
#define DD 128
#define BHH 32
#define QT 64   // queries per block (32 per wave x 2 waves)
#define KT 64   // keys per K tile

typedef short v8s __attribute__((ext_vector_type(8)));   // 8 bf16 (raw bits)
typedef short v4s __attribute__((ext_vector_type(4)));   // 4 bf16
typedef float v4f __attribute__((ext_vector_type(4)));
typedef float v16f __attribute__((ext_vector_type(16)));
typedef unsigned int u32;
typedef u32 u32x2 __attribute__((ext_vector_type(2)));
typedef u32 u32x4 __attribute__((ext_vector_type(4)));

__device__ __forceinline__ unsigned short f2bf(float x) {
  unsigned u = __builtin_bit_cast(unsigned, x);
  u += 0x7fffu + ((u >> 16) & 1u);   // RNE
  return (unsigned short)(u >> 16);
}

// v_cvt_pk_bf16_f32: 2 f32 -> packed 2x bf16 (RNE), single VALU op.
__device__ __forceinline__ u32 pk2(float a, float b) {
  u32 r;
  asm("v_cvt_pk_bf16_f32 %0, %1, %2" : "=v"(r) : "v"(a), "v"(b));
  return r;
}

// async global->LDS DMA, 16B/lane: LDS dst is wave-uniform base + lane*16.
__device__ __forceinline__ void gl_lds16(const unsigned short* g, unsigned short* l) {
  __builtin_amdgcn_global_load_lds((const unsigned int*)g, (unsigned int*)l, 16, 0, 0);
}

// Fused prep, one dispatch. grid=(32,2,64):
//  z >= 32: Kfrag pack: frag(kb32,kc) lane l elem j = K[kb32*32+(l&31)][kc*16+(l>>5)*8+j]
//  z <  32: Vfrag pack: frag(kt16,nc) lane l elem j = V[kt16*16+(l>>5)*8+j][nc*32+(l&31)]
__global__ __launch_bounds__(256) void prep(const float* __restrict__ K, const float* __restrict__ V,
                     unsigned short* __restrict__ Kb, unsigned short* __restrict__ Vt) {
  const int z = blockIdx.z;
  const int tid = threadIdx.x;
  if (z >= BHH) {
    const int bh = z - BHH;
    const int kb32 = blockIdx.y * 32 + blockIdx.x;   // 0..63 (32-key block)
    const int m = tid & 31, kc = tid >> 5;           // kc 0..7
    const float* src = K + ((size_t)bh * NN + kb32 * 32 + m) * DD + kc * 16;
    v4f a0 = *(const v4f*)(src);
    v4f a1 = *(const v4f*)(src + 4);
    v4f a2 = *(const v4f*)(src + 8);
    v4f a3 = *(const v4f*)(src + 12);
    u32x4 w0 = { pk2(a0[0], a0[1]), pk2(a0[2], a0[3]), pk2(a1[0], a1[1]), pk2(a1[2], a1[3]) };
    u32x4 w1 = { pk2(a2[0], a2[1]), pk2(a2[2], a2[3]), pk2(a3[0], a3[1]), pk2(a3[2], a3[3]) };
    unsigned short* base = Kb + (((size_t)bh * 64 + kb32) * 8 + kc) * 512;
    *(u32x4*)(base + (size_t)m * 8) = w0;          // hi=0 lanes
    *(u32x4*)(base + (size_t)(32 + m) * 8) = w1;   // hi=1 lanes
    return;
  }
  __shared__ __align__(16) unsigned short t[64 * 68];  // [dloc][nloc], stride 68
  const int bh = z;
  const int n0b = blockIdx.x, d0b = blockIdx.y;        // 64-blocks
  const int c16 = tid & 15, r4 = tid >> 4;
  const float* src = V + ((size_t)bh * NN + n0b * 64 + r4 * 4) * DD + d0b * 64 + c16 * 4;
  v4f f0 = *(const v4f*)(src);
  v4f f1 = *(const v4f*)(src + DD);
  v4f f2 = *(const v4f*)(src + 2 * DD);
  v4f f3 = *(const v4f*)(src + 3 * DD);
#pragma unroll
  for (int j = 0; j < 4; j++) {
    u32x2 w = { pk2(f0[j], f1[j]), pk2(f2[j], f3[j]) };
    *(u32x2*)(t + (c16 * 4 + j) * 68 + r4 * 4) = w;    // t[d][n] = V[n][d]
  }
  __syncthreads();
  unsigned short* Vfb = Vt + (size_t)bh * (512u * 512);
#pragma unroll
  for (int p = 0; p < 2; p++) {
    const int fid = p * 4 + (tid >> 6);       // 0..7
    const int ktl = fid >> 1, ncl = fid & 1;
    const int lane = tid & 63;
    const int dloc = ncl * 32 + (lane & 31);
    const int nloc = ktl * 16 + (lane >> 5) * 8;
    v4s x0 = *(const v4s*)(t + dloc * 68 + nloc);
    v4s x1 = *(const v4s*)(t + dloc * 68 + nloc + 4);
    v8s o = { x0[0], x0[1], x0[2], x0[3], x1[0], x1[1], x1[2], x1[3] };
    const size_t fi = (size_t)(n0b * 4 + ktl) * 4 + (d0b * 2 + ncl);
    *(v8s*)(Vfb + fi * 512 + (size_t)lane * 8) = o;
  }
}

// Flash-style sink+sliding-window attention, f32 in/out, bf16 MFMA compute.
// R7: key-split across BLOCKS. r3-r6 invariant: per-wave efficiency x waves
// is pinned, and q-ownership caps waves at 8/CU (B*H=32 is parallelism-
// starved). Plain-exp2 softmax => disjoint-key partials merge by addition:
// SPLIT grid = 32bh x 32qtile x 2 key-halves = 2048 blocks (8/CU offered,
// 5/CU LDS-capped -> ~10-16 waves/CU vs r6's 6). Half A writes raw f32
// numerator to O + lsA; half B writes bf16 numerator + lsB; merge kernel
// normalizes O=(O+pB)/(lA+lB). Inner loop = r6 verified (DMA K dbuf,
// register V frags, swapped-QK 32x32, cvt_pk+permlane P-pack, setprio).
// mfma_f32_32x32x16_bf16 layouts: A: lane holds A[m=lane&31][k=(lane>>5)*8+j]
// B: B[k=(lane>>5)*8+j][n=lane&31]; C/D: D[row=(reg&3)+8*(reg>>2)+4*(lane>>5)]
// [col=lane&31]  (m74/m101-verified mapping).
template <bool SPLIT>
__global__ __launch_bounds__(128, 2) void attn(
    const float* __restrict__ Q, const unsigned short* __restrict__ Kb,
    const unsigned short* __restrict__ Vfr,
    const int* __restrict__ nsp, const int* __restrict__ wsp,
    float* __restrict__ O, unsigned short* __restrict__ pB,
    float* __restrict__ lsA, float* __restrict__ lsB) {
  const int ns = nsp[0], win = wsp[0];
  const int x = blockIdx.x;
  int bh, hf = 0, qis[2], njobs;
  if constexpr (SPLIT) {
    const int xcd = x & 7, r = x >> 3;      // r 0..255
    bh = xcd + 8 * (r >> 6);                // 4 bh per XCD (L2 locality)
    const int inner = r & 63;               // 32 qi x 2 halves
    qis[0] = inner >> 1; qis[1] = 0; hf = inner & 1; njobs = 1;
  } else {
    const int xcd = x & 7, slot = x >> 3;   // 768 blocks, r6 mono decode
    bh = xcd + 8 * (slot / 24);
    const int jobid = slot % 24;
    if (jobid < 16) { njobs = 1; qis[0] = 31 - jobid; qis[1] = 0; }
    else { int p = jobid - 16; njobs = 2; qis[0] = 15 - p; qis[1] = p; }
  }

  const int tid = threadIdx.x;
  const int w = tid >> 6;      // wave 0..1 (q rows w*32..+31 of the job)
  const int l = tid & 63;
  const int m = l & 31;
  const int hi = l >> 5;
  const int rbase = 4 * hi;

  __shared__ __align__(16) unsigned short Kl[2][16 * 512];  // 2 x 16KB dbuf

  const float csc = 0.088388347648318447f * 1.4426950408889634f;  // 1/sqrt(128)*log2(e)

  const unsigned short* Vfb = Vfr + (size_t)bh * (512u * 512);

  // P C-layout -> PV A-frag via cvt_pk + permlane32_swap (r4/r6-verified)
  auto mkpa = [&](float a0, float a1, float a2, float a3,
                  float b0, float b1, float b2, float b3) -> v8s {
    u32x2 r02 = __builtin_amdgcn_permlane32_swap(pk2(a0, a1), pk2(b0, b1), false, false);
    u32x2 r13 = __builtin_amdgcn_permlane32_swap(pk2(a2, a3), pk2(b2, b3), false, false);
    u32x4 pw = { r02[0], r13[0], r02[1], r13[1] };
    return __builtin_bit_cast(v8s, pw);
  };

  for (int ji = 0; ji < njobs; ji++) {
    const int q0 = qis[ji] * QT;
    const int qrow0w = q0 + w * 32;  // this wave's 32 query rows
    const int qi = qrow0w + m;       // this lane's query (S^T col)

    // Q B-frags, pre-scaled: lane holds Q[qi][kc*16 + hi*8 + j]*csc
    v8s qf[8];
    {
      const float* qb = Q + ((size_t)bh * NN + qi) * DD + hi * 8;
#pragma unroll
      for (int kc = 0; kc < 8; kc++) {
        v4f a = *(const v4f*)(qb + kc * 16);
        v4f b = *(const v4f*)(qb + kc * 16 + 4);
        u32x4 pw = { pk2(a[0] * csc, a[1] * csc), pk2(a[2] * csc, a[3] * csc),
                     pk2(b[0] * csc, b[1] * csc), pk2(b[2] * csc, b[3] * csc) };
        qf[kc] = __builtin_bit_cast(v8s, pw);
      }
    }

    float lsum = 0.f;
    v16f oa[4];
#pragma unroll
    for (int nc = 0; nc < 4; nc++) oa[nc] = (v16f)(0.f);

    // ---- tile range (contiguous, r3-verified); SPLIT: contiguous halves ----
    const int wstart = q0 - win + 1;
    const bool sink16_all = (wstart > KT - 1) && (ns <= 16);
    const int kb_lo = sink16_all ? ((wstart >> 6) << 6) : 0;
    const int kb_hi = q0 + QT;
    int kb_begin = kb_lo, kb_end = kb_hi;
    bool do_sink = sink16_all;
    if constexpr (SPLIT) {
      const int T = (kb_hi - kb_lo) >> 6;
      const int TA = (T + 1) >> 1;
      if (hf == 0) { kb_end = kb_lo + TA * KT; do_sink = false; }
      else         { kb_begin = kb_lo + TA * KT; }   // sink rides with B
    }

    // issue this wave's 8 K-frags (ct=w half of the tile) via DMA
    auto issueK = [&](int kb, int buf) {
      const unsigned short* src =
          Kb + (((size_t)bh * 64 + (kb >> 5) + w) * 8) * 512 + (size_t)l * 8;
      unsigned short* dst = &Kl[buf][(w * 8) * 512];
#pragma unroll
      for (int i = 0; i < 8; i++)
        gl_lds16(src + (size_t)i * 512, dst + i * 512);
    };

    const bool haveloop = kb_begin < kb_end;   // block-uniform
    if (haveloop) issueK(kb_begin, 0);         // in flight during sink compute

    if (do_sink) {
      // sink tile: keys 0..31 in one 32x32 block (keys >= ns masked)
      v8s kf0[8];
#pragma unroll
      for (int kc = 0; kc < 8; kc++)
        kf0[kc] = *(const v8s*)(Kb + ((size_t)bh * 64 * 8 + kc) * 512 + (size_t)l * 8);
      v16f s = (v16f)(0.f);
#pragma unroll
      for (int kc = 0; kc < 8; kc++)
        s = __builtin_amdgcn_mfma_f32_32x32x16_bf16(kf0[kc], qf[kc], s, 0, 0, 0);
#pragma unroll
      for (int reg = 0; reg < 16; reg++) {
        const int kj = (reg & 3) + 8 * (reg >> 2) + rbase;
        const bool valid = (kj < ns) && (kj <= qi);
        s[reg] = valid ? __builtin_amdgcn_exp2f(s[reg]) : 0.f;
      }
      lsum += (((s[0] + s[1]) + (s[2] + s[3])) + ((s[4] + s[5]) + (s[6] + s[7])))
            + (((s[8] + s[9]) + (s[10] + s[11])) + ((s[12] + s[13]) + (s[14] + s[15])));
      v8s pa = mkpa(s[0], s[1], s[2], s[3], s[4], s[5], s[6], s[7]);
#pragma unroll
      for (int nc = 0; nc < 4; nc++) {
        v8s vf = *(const v8s*)(Vfb + (size_t)nc * 512 + (size_t)l * 8);
        oa[nc] = __builtin_amdgcn_mfma_f32_32x32x16_bf16(pa, vf, oa[nc], 0, 0, 0);
      }
    }

    if (haveloop) {
      asm volatile("s_waitcnt vmcnt(0)" ::: "memory");
      __syncthreads();  // first tile staged (both waves' DMA landed)
      int cur = 0;
      for (int kb = kb_begin; kb < kb_end; kb += KT) {
        if (kb + KT < kb_end) issueK(kb + KT, cur ^ 1);  // 0-reg prefetch DMA
        // V frags: 16 contiguous 1KB loads, consumed after QK+softmax
        v8s vf[16];
#pragma unroll
        for (int i = 0; i < 16; i++) {
          const int kt = i >> 2, nc = i & 3;
          vf[i] = *(const v8s*)(Vfb + ((size_t)((kb >> 4) + kt) * 4 + nc) * 512 + (size_t)l * 8);
        }

#pragma unroll
        for (int ct = 0; ct < 2; ct++) {
          // S^T(32x32): lane holds col q=qi, rows key = kb+ct*32+(reg&3)+8*(reg>>2)+rbase
          v16f s = (v16f)(0.f);
          __builtin_amdgcn_s_setprio(1);
#pragma unroll
          for (int kc = 0; kc < 8; kc++) {
            v8s kfr = *(const v8s*)(&Kl[cur][(ct * 8 + kc) * 512 + l * 8]);
            s = __builtin_amdgcn_mfma_f32_32x32x16_bf16(kfr, qf[kc], s, 0, 0, 0);
          }
          __builtin_amdgcn_s_setprio(0);

          const int kbct = kb + ct * 32;
          const bool full = (kbct + 31 <= qrow0w) && (kbct >= qrow0w + 32 - win);
          if (full) {
#pragma unroll
            for (int reg = 0; reg < 16; reg++) s[reg] = __builtin_amdgcn_exp2f(s[reg]);
          } else {
#pragma unroll
            for (int reg = 0; reg < 16; reg++) {
              const int kj = kbct + (reg & 3) + 8 * (reg >> 2) + rbase;
              const bool valid = (kj <= qi) && ((kj < ns) || (qi - kj < win));
              s[reg] = valid ? __builtin_amdgcn_exp2f(s[reg]) : 0.f;
            }
          }
          lsum += (((s[0] + s[1]) + (s[2] + s[3])) + ((s[4] + s[5]) + (s[6] + s[7])))
                + (((s[8] + s[9]) + (s[10] + s[11])) + ((s[12] + s[13]) + (s[14] + s[15])));

          v8s pa0 = mkpa(s[0], s[1], s[2], s[3], s[4], s[5], s[6], s[7]);
          v8s pa1 = mkpa(s[8], s[9], s[10], s[11], s[12], s[13], s[14], s[15]);

          __builtin_amdgcn_s_setprio(1);
#pragma unroll
          for (int ktl = 0; ktl < 2; ktl++) {
            const v8s pf = ktl ? pa1 : pa0;
#pragma unroll
            for (int nc = 0; nc < 4; nc++)
              oa[nc] = __builtin_amdgcn_mfma_f32_32x32x16_bf16(pf, vf[(ct * 2 + ktl) * 4 + nc],
                                                               oa[nc], 0, 0, 0);
          }
          __builtin_amdgcn_s_setprio(0);
        }

        asm volatile("s_waitcnt vmcnt(0)" ::: "memory");  // next-tile DMA landed
        __syncthreads();  // both waves done with Kl[cur]
        cur ^= 1;
      }
    }

    // ---- epilogue ----
    float lt = lsum + __shfl_xor(lsum, 32, 64);  // full row sum for q=qi (this block's keys)
    if constexpr (SPLIT) {
      if (hf == 0) {
        float* ob = O + ((size_t)bh * NN + qrow0w) * DD;   // raw f32 numerator
#pragma unroll
        for (int reg = 0; reg < 16; reg++) {
          const int row = (reg & 3) + 8 * (reg >> 2) + rbase;
#pragma unroll
          for (int nc = 0; nc < 4; nc++)
            ob[(size_t)row * DD + nc * 32 + m] = oa[nc][reg];
        }
        if (hi == 0) lsA[((size_t)bh << 11) + qrow0w + m] = lt;
      } else {
        unsigned short* pb = pB + ((size_t)bh * NN + qrow0w) * DD;  // bf16 numerator
#pragma unroll
        for (int reg = 0; reg < 16; reg++) {
          const int row = (reg & 3) + 8 * (reg >> 2) + rbase;
#pragma unroll
          for (int nc = 0; nc < 4; nc++)
            pb[(size_t)row * DD + nc * 32 + m] = f2bf(oa[nc][reg]);
        }
        if (hi == 0) lsB[((size_t)bh << 11) + qrow0w + m] = lt;
      }
    } else {
      const float inv = 1.f / lt;
      float* ob = O + ((size_t)bh * NN + qrow0w) * DD;
#pragma unroll
      for (int reg = 0; reg < 16; reg++) {
        const int row = (reg & 3) + 8 * (reg >> 2) + rbase;
        const float iv = __shfl(inv, row, 64);   // lane 'row' holds q=qrow0w+row
#pragma unroll
        for (int nc = 0; nc < 4; nc++)
          ob[(size_t)row * DD + nc * 32 + m] = oa[nc][reg] * iv;
      }
    }
  }
}

// O = (O + bf16(pB)) / (lsA + lsB), 2M float4 grid-stride.
__global__ __launch_bounds__(256) void merge(float* __restrict__ O,
    const unsigned short* __restrict__ pB, const float* __restrict__ lsA,
    const float* __restrict__ lsB) {
  const int total4 = BHH * NN * DD / 4;   // 2,097,152
  for (int i = blockIdx.x * 256 + threadIdx.x; i < total4; i += gridDim.x * 256) {
    v4f o = ((const v4f*)O)[i];
    v4s b = ((const v4s*)pB)[i];
    const int row = i >> 5;               // 32 float4 per 128-d row
    const float inv = 1.f / (lsA[row] + lsB[row]);
    v4f r;
#pragma unroll
    for (int j = 0; j < 4; j++) {
      const float bf = __builtin_bit_cast(float, (u32)((unsigned short)b[j]) << 16);
      r[j] = (o[j] + bf) * inv;
    }
    ((v4f*)O)[i] = r;
  }
}

extern "C" void kernel_launch(void* const* d_in, const int* in_sizes, int n_in,
                              void* d_out, int out_size, void* d_ws, size_t ws_size,
                              hipStream_t stream) {
  const float* q = (const float*)d_in[0];
  const float* k = (const float*)d_in[1];
  const float* v = (const float*)d_in[2];
  const int* nsp = (const int*)d_in[3];
  const int* wsp = (const int*)d_in[4];
  float* out = (float*)d_out;

  const size_t MB16 = 16777216;                    // 16 MiB
  const size_t LS = (size_t)BHH * NN * 4;          // 262144 B per lsum array
  char* ws = (char*)d_ws;
  unsigned short* kfrag = (unsigned short*)ws;
  unsigned short* vfrag = (unsigned short*)(ws + MB16);

  if (ws_size >= 3 * MB16 + 2 * LS) {
    unsigned short* pB = (unsigned short*)(ws + 2 * MB16);
    float* lsA = (float*)(ws + 3 * MB16);
    float* lsB = (float*)(ws + 3 * MB16 + LS);
    prep<<<dim3(32, 2, 2 * BHH), 256, 0, stream>>>(k, v, kfrag, vfrag);
    attn<true><<<2048, 128, 0, stream>>>(q, kfrag, vfrag, nsp, wsp, out, pB, lsA, lsB);
    merge<<<2048, 256, 0, stream>>>(out, pB, lsA, lsB);
  } else {
    // mono fallback (r6 structure; ws >= 32 MiB established by rounds 2-6)
    prep<<<dim3(32, 2, 2 * BHH), 256, 0, stream>>>(k, v, kfrag, vfrag);
    attn<false><<<BHH * 24, 128, 0, stream>>>(q, kfrag, vfrag, nsp, wsp, out,
                                              nullptr, nullptr, nullptr);
  }
}